// Round 4
// baseline (684.149 us; speedup 1.0000x reference)
//
#include <hip/hip_runtime.h>
#include <math.h>

typedef unsigned short u16;
typedef unsigned int   u32;
typedef float f32x4 __attribute__((ext_vector_type(4)));
typedef short bfx8  __attribute__((ext_vector_type(8)));

#define NB   2
#define CCH  128
#define HS   48
#define LL   2304        // 48*48
#define KP   1152        // 128*3*3
#define KW   2048        // 128*4*4
#define HO   96
#define PIX  9216        // 96*96
#define TB_LD 4608       // Tb (bf16 attention) row stride in u16 elements

// Workspace byte offsets (total ~55.6 MB)
#define PHI_B 0                  // P hi  bf16: 2304*1152*2
#define PLO_B 5308416            // P lo  bf16
#define WT_B  10616832           // W^T   bf16: 2048*2304*2
#define T_B   20054016           // T fp32: 2304*2304*4 (bf16 Tb aliased)
#define YB_B  41287680           // y fp32: 2*128*96*96*4
#define NRM_B 50724864           // 1/norms: 2*2304*4
#define MM_B  50743296           // mm flags: 2*2304*4
#define YT_B  50761728           // yT bf16 [2][9216][128]
#define WF_B  55480320           // fuse weights bf16 [64][9][128]

__device__ __forceinline__ u16 f2bf(float f) {      // round-to-nearest-even
    u32 u = __float_as_uint(f);
    u32 r = (u + 0x7fffu + ((u >> 16) & 1u)) >> 16;
    return (u16)r;
}
__device__ __forceinline__ float bf2f(u16 h) {
    return __uint_as_float(((u32)h) << 16);
}
__device__ __forceinline__ void gll16(const void* g, void* l) {
    __builtin_amdgcn_global_load_lds((const __attribute__((address_space(1))) void*)g,
                                     (__attribute__((address_space(3))) void*)l, 16, 0, 0);
}

// ---------------------------------------------------------------------------
__global__ __launch_bounds__(256) void build_P_k(const float* __restrict__ x2,
                                                 u16* __restrict__ Ph, u16* __restrict__ Pl, int n) {
    int idx = blockIdx.x * 256 + threadIdx.x;
    int k = idx % KP, p = idx / KP;
    int c = k / 9, t = k - c * 9;
    int di = t / 3, dj = t - di * 3;
    int i = p / HS, j = p - (p / HS) * HS;
    int ii = i + di - 1, jj = j + dj - 1;
    float v = 0.0f;
    if (ii >= 0 && ii < HS && jj >= 0 && jj < HS)
        v = x2[((n * CCH + c) * HS + ii) * HS + jj];
    u16 h = f2bf(v);
    Ph[idx] = h;
    Pl[idx] = f2bf(v - bf2f(h));
}

// ---------------------------------------------------------------------------
// Stores RECIPROCAL of max(norm,1e-4) + mask-zero flag.
__global__ __launch_bounds__(256) void norms_mm_k(const float* __restrict__ x2,
                                                  const float* __restrict__ mask,
                                                  float* __restrict__ rnorm,
                                                  float* __restrict__ mmb, int n) {
    int wid  = (blockIdx.x * 256 + threadIdx.x) >> 6;
    int lane = threadIdx.x & 63;
    if (wid >= LL) return;
    int i = wid / HS, j = wid - (wid / HS) * HS;
    float s = 0.0f;
    for (int k = lane; k < KP; k += 64) {
        int c = k / 9, t = k - (k / 9) * 9;
        int di = t / 3, dj = t - di * 3;
        int ii = i + di - 1, jj = j + dj - 1;
        if (ii >= 0 && ii < HS && jj >= 0 && jj < HS) {
            float x = x2[((n * CCH + c) * HS + ii) * HS + jj];
            s += x * x;
        }
    }
    #pragma unroll
    for (int o = 32; o; o >>= 1) s += __shfl_down(s, o);
    if (lane == 0) {
        rnorm[n * LL + wid] = 1.0f / fmaxf(sqrtf(s), 1e-4f);
        float msum = 0.0f;
        for (int di = -1; di <= 1; di++)
            for (int dj = -1; dj <= 1; dj++) {
                int ii = i + di, jj = j + dj;
                if (ii >= 0 && ii < HS && jj >= 0 && jj < HS)
                    msum += mask[(n * HS + ii) * HS + jj];
            }
        mmb[n * LL + wid] = (msum == 0.0f) ? 1.0f : 0.0f;
    }
}

// ---------------------------------------------------------------------------
// T[p][l] += P[p].P[l] over K-chunk (split-K x2, atomic). Split-bf16 MFMA.
// LDS layout: 16-row groups, K-major within group -> conflict-free b128 reads.
__global__ __launch_bounds__(256) void gemm1_k(const u16* __restrict__ Ph, const u16* __restrict__ Pl,
                                               float* __restrict__ T, int n) {
    __shared__ __align__(16) u16 Ah[4096], Al[4096], Bh[4096], Bl[4096];
    int tid = threadIdx.x, w = tid >> 6, lane = tid & 63;
    int m0 = blockIdx.x * 128, n0 = blockIdx.y * 128;
    int koff = blockIdx.z * 576;
    int srow = lane & 15, sk = (lane >> 4) * 8;     // staging: row-in-group, k-chunk
    size_t a1 = (size_t)(m0 + w * 16 + srow) * KP + koff + sk;
    size_t a2 = a1 + (size_t)64 * KP;
    size_t b1 = (size_t)(n0 + w * 16 + srow) * KP + koff + sk;
    size_t b2 = b1 + (size_t)64 * KP;
    int wm = (w >> 1) * 64, wn = (w & 1) * 64;
    int ga = (w >> 1) * 4, gb = (w & 1) * 4;        // fragment group bases
    f32x4 acc[4][4];
    #pragma unroll
    for (int i = 0; i < 4; i++)
        #pragma unroll
        for (int j = 0; j < 4; j++) acc[i][j] = (f32x4)0.0f;

    for (int k0 = 0; k0 < 576; k0 += 32) {
        if (k0) __syncthreads();
        gll16(Ph + a1 + k0, Ah + w * 512);
        gll16(Ph + a2 + k0, Ah + (w + 4) * 512);
        gll16(Pl + a1 + k0, Al + w * 512);
        gll16(Pl + a2 + k0, Al + (w + 4) * 512);
        gll16(Ph + b1 + k0, Bh + w * 512);
        gll16(Ph + b2 + k0, Bh + (w + 4) * 512);
        gll16(Pl + b1 + k0, Bl + w * 512);
        gll16(Pl + b2 + k0, Bl + (w + 4) * 512);
        __syncthreads();
        bfx8 ah[4], al[4], bh[4], bl[4];
        #pragma unroll
        for (int i = 0; i < 4; i++) {
            ah[i] = *(const bfx8*)&Ah[(ga + i) * 512 + lane * 8];
            al[i] = *(const bfx8*)&Al[(ga + i) * 512 + lane * 8];
        }
        #pragma unroll
        for (int j = 0; j < 4; j++) {
            bh[j] = *(const bfx8*)&Bh[(gb + j) * 512 + lane * 8];
            bl[j] = *(const bfx8*)&Bl[(gb + j) * 512 + lane * 8];
        }
        #pragma unroll
        for (int i = 0; i < 4; i++)
            #pragma unroll
            for (int j = 0; j < 4; j++) {
                acc[i][j] = __builtin_amdgcn_mfma_f32_16x16x32_bf16(ah[i], bh[j], acc[i][j], 0, 0, 0);
                acc[i][j] = __builtin_amdgcn_mfma_f32_16x16x32_bf16(ah[i], bl[j], acc[i][j], 0, 0, 0);
                acc[i][j] = __builtin_amdgcn_mfma_f32_16x16x32_bf16(al[i], bh[j], acc[i][j], 0, 0, 0);
            }
    }
    #pragma unroll
    for (int j = 0; j < 4; j++) {
        int col = n0 + wn + j * 16 + (lane & 15);
        #pragma unroll
        for (int i = 0; i < 4; i++) {
            int rbase = m0 + wm + i * 16 + (lane >> 4) * 4;
            #pragma unroll
            for (int r = 0; r < 4; r++)
                atomicAdd(&T[(size_t)(rbase + r) * LL + col], acc[i][j][r]);
        }
    }
}

// ---------------------------------------------------------------------------
// Row softmax; applies 1/norm per column here (gemm1 is now un-normalized).
__global__ __launch_bounds__(256) void softmax_k(const float* __restrict__ T,
                                                 u16* __restrict__ Tb,
                                                 const float* __restrict__ rnorm,
                                                 const float* __restrict__ mmb,
                                                 const float* __restrict__ mask_all, int n) {
    int p = blockIdx.x, tid = threadIdx.x;
    __shared__ float red[8];
    const float* row = T + (size_t)p * LL;
    u16* orow = Tb + (size_t)p * TB_LD;
    float ma = mask_all[n * LL + p];
    float v[9], mmr[9];
    float mx = -3.0e38f;
    #pragma unroll
    for (int e = 0; e < 9; e++) {
        int l = tid + e * 256;
        float m_ = mmb[n * LL + l];
        mmr[e] = m_;
        float s = row[l] * rnorm[n * LL + l] * m_ * ma * 10.0f;
        v[e] = s;
        mx = fmaxf(mx, s);
    }
    #pragma unroll
    for (int o = 32; o; o >>= 1) mx = fmaxf(mx, __shfl_down(mx, o));
    int wid = tid >> 6, lane = tid & 63;
    if (lane == 0) red[wid] = mx;
    __syncthreads();
    mx = fmaxf(fmaxf(red[0], red[1]), fmaxf(red[2], red[3]));
    float sum = 0.0f;
    #pragma unroll
    for (int e = 0; e < 9; e++) { v[e] = __expf(v[e] - mx); sum += v[e]; }
    #pragma unroll
    for (int o = 32; o; o >>= 1) sum += __shfl_down(sum, o);
    if (lane == 0) red[4 + wid] = sum;
    __syncthreads();
    float inv = 1.0f / (red[4] + red[5] + red[6] + red[7]);
    int pi = p / HS, pj = p - (p / HS) * HS;
    #pragma unroll
    for (int e = 0; e < 9; e++) {
        int l = tid + e * 256;
        int li = l / HS, lj = l - (l / HS) * HS;
        bool nb = (li == pi && (lj == pj - 1 || lj == pj + 1)) ||
                  (lj == pj && (li == pi - 1 || li == pi + 1));
        float z = v[e] * inv * (nb ? 1.5f : 1.0f) * mmr[e] * ma;
        orow[l] = f2bf(fmaxf(z, 1e-8f));
    }
}

// ---------------------------------------------------------------------------
__global__ __launch_bounds__(256) void build_W_k(const float* __restrict__ x1,
                                                 u16* __restrict__ Wt, int n) {
    int idx = blockIdx.x * 256 + threadIdx.x;
    int l = idx % LL, f = idx / LL;
    int c = f >> 4, ky = (f >> 2) & 3, kx = f & 3;
    int li = l / HS, lj = l - (l / HS) * HS;
    int yy = 2 * li - 1 + ky, xx = 2 * lj - 1 + kx;
    float v = 0.0f;
    if (yy >= 0 && yy < HO && xx >= 0 && xx < HO)
        v = x1[((n * CCH + c) * HO + yy) * HO + xx];
    Wt[idx] = f2bf(v);
}

// ---------------------------------------------------------------------------
// V[p][f] = sum_l Tb[p][l]*Wt[f][l], split-K x4; overlap-add 0.25*V (atomic).
__global__ __launch_bounds__(256) void gemm2_k(const u16* __restrict__ Tb, const u16* __restrict__ Wt,
                                               float* __restrict__ yb, int n) {
    __shared__ __align__(16) u16 As[4096], Bs[4096];
    int tid = threadIdx.x, w = tid >> 6, lane = tid & 63;
    int m0 = blockIdx.x * 128, n0 = blockIdx.y * 128;
    int koff = blockIdx.z * 576;
    int srow = lane & 15, sk = (lane >> 4) * 8;
    size_t a1 = (size_t)(m0 + w * 16 + srow) * TB_LD + koff + sk;
    size_t a2 = a1 + (size_t)64 * TB_LD;
    size_t b1 = (size_t)(n0 + w * 16 + srow) * LL + koff + sk;
    size_t b2 = b1 + (size_t)64 * LL;
    int wm = (w >> 1) * 64, wn = (w & 1) * 64;
    int ga = (w >> 1) * 4, gb = (w & 1) * 4;
    f32x4 acc[4][4];
    #pragma unroll
    for (int i = 0; i < 4; i++)
        #pragma unroll
        for (int j = 0; j < 4; j++) acc[i][j] = (f32x4)0.0f;

    for (int k0 = 0; k0 < 576; k0 += 32) {
        if (k0) __syncthreads();
        gll16(Tb + a1 + k0, As + w * 512);
        gll16(Tb + a2 + k0, As + (w + 4) * 512);
        gll16(Wt + b1 + k0, Bs + w * 512);
        gll16(Wt + b2 + k0, Bs + (w + 4) * 512);
        __syncthreads();
        bfx8 af[4], bf[4];
        #pragma unroll
        for (int i = 0; i < 4; i++) af[i] = *(const bfx8*)&As[(ga + i) * 512 + lane * 8];
        #pragma unroll
        for (int j = 0; j < 4; j++) bf[j] = *(const bfx8*)&Bs[(gb + j) * 512 + lane * 8];
        #pragma unroll
        for (int i = 0; i < 4; i++)
            #pragma unroll
            for (int j = 0; j < 4; j++)
                acc[i][j] = __builtin_amdgcn_mfma_f32_16x16x32_bf16(af[i], bf[j], acc[i][j], 0, 0, 0);
    }
    #pragma unroll
    for (int j = 0; j < 4; j++) {
        int f = n0 + wn + j * 16 + (lane & 15);
        int c = f >> 4, ky = (f >> 2) & 3, kx = f & 3;
        #pragma unroll
        for (int i = 0; i < 4; i++) {
            int rbase = m0 + wm + i * 16 + (lane >> 4) * 4;
            #pragma unroll
            for (int r = 0; r < 4; r++) {
                int p = rbase + r;
                int pi = p / HS, pj = p - (p / HS) * HS;
                int yy = 2 * pi - 1 + ky, xx = 2 * pj - 1 + kx;
                if (yy >= 0 && yy < HO && xx >= 0 && xx < HO)
                    atomicAdd(&yb[((size_t)(n * CCH + c) * HO + yy) * HO + xx],
                              0.25f * acc[i][j][r]);
            }
        }
    }
}

// ---------------------------------------------------------------------------
__global__ __launch_bounds__(256) void y2bf_k(const float* __restrict__ yb,
                                              u16* __restrict__ yT) {
    __shared__ float lt[32][130];
    int blk = blockIdx.x;
    int n  = blk / (PIX / 32);
    int pq0 = (blk - n * (PIX / 32)) * 32;
    int tid = threadIdx.x;
    #pragma unroll
    for (int i = tid; i < 32 * 128; i += 256) {
        int c = i >> 5, p = i & 31;
        lt[p][c] = yb[((size_t)(n * CCH + c)) * PIX + pq0 + p];
    }
    __syncthreads();
    #pragma unroll
    for (int i = tid; i < 32 * 128; i += 256) {
        int p = i >> 7, c = i & 127;
        yT[((size_t)(n * PIX + pq0 + p)) * CCH + c] = f2bf(lt[p][c]);
    }
}

__global__ __launch_bounds__(256) void wprep_k(const float* __restrict__ fw,
                                               u16* __restrict__ Wf) {
    int idx = blockIdx.x * 256 + threadIdx.x;
    int c = idx & 127;
    int tap = (idx >> 7) % 9;
    int go = idx / (128 * 9);
    Wf[idx] = f2bf(fw[((size_t)go * 128 + c) * 9 + tap]);
}

// ---------------------------------------------------------------------------
__global__ __launch_bounds__(256) void fuse_mfma_k(const u16* __restrict__ yT,
                                                   const u16* __restrict__ Wf,
                                                   const float* __restrict__ fb,
                                                   float* __restrict__ out) {
    int n = blockIdx.z, g = blockIdx.y;
    const int d = 1 << g;
    int tid = threadIdx.x, wv = tid >> 6, lane = tid & 63;
    int pix0 = blockIdx.x * 64 + wv * 16;
    int h = pix0 / HO, w0 = pix0 - h * HO;
    int m = lane & 15, q = lane >> 4;
    int oc = m;
    const u16* brow = Wf + ((size_t)(g * 16 + oc) * 9) * CCH + q * 8;
    f32x4 acc = (f32x4)0.0f;

    #pragma unroll
    for (int tap = 0; tap < 9; tap++) {
        int dy = (tap / 3 - 1) * d, dx = (tap % 3 - 1) * d;
        int hh = h + dy;
        int ww = w0 + m + dx;
        bool v = (hh >= 0) & (hh < HO) & (ww >= 0) & (ww < HO);
        const u16* arow = yT + ((size_t)(n * PIX + hh * HO + ww)) * CCH + q * 8;
        const u16* bt = brow + tap * CCH;
        #pragma unroll
        for (int c0 = 0; c0 < CCH; c0 += 32) {
            bfx8 af = (bfx8)0;
            if (v) af = *(const bfx8*)(arow + c0);
            bfx8 bf = *(const bfx8*)(bt + c0);
            acc = __builtin_amdgcn_mfma_f32_16x16x32_bf16(af, bf, acc, 0, 0, 0);
        }
    }
    float bias = fb[g * 16 + oc];
    f32x4 o;
    #pragma unroll
    for (int r = 0; r < 4; r++) o[r] = fmaxf(acc[r] + bias, 0.0f);
    size_t oi = ((size_t)(n * 64 + g * 16 + oc)) * PIX + pix0 + q * 4;
    *(f32x4*)&out[oi] = o;
}

// ---------------------------------------------------------------------------
extern "C" void kernel_launch(void* const* d_in, const int* in_sizes, int n_in,
                              void* d_out, int out_size, void* d_ws, size_t ws_size,
                              hipStream_t stream) {
    const float* x1       = (const float*)d_in[0];
    const float* x2       = (const float*)d_in[1];
    const float* mask     = (const float*)d_in[2];
    const float* mask_all = (const float*)d_in[3];
    const float* fw       = (const float*)d_in[4];
    const float* fb       = (const float*)d_in[5];
    float* out = (float*)d_out;
    char* wsb  = (char*)d_ws;

    u16*   Phi   = (u16*)(wsb + PHI_B);
    u16*   Plo   = (u16*)(wsb + PLO_B);
    u16*   Wt    = (u16*)(wsb + WT_B);
    float* T     = (float*)(wsb + T_B);
    u16*   Tb    = (u16*)(wsb + T_B);
    float* yb    = (float*)(wsb + YB_B);
    float* rnorm = (float*)(wsb + NRM_B);
    float* mmb   = (float*)(wsb + MM_B);
    u16*   yT    = (u16*)(wsb + YT_B);
    u16*   Wf    = (u16*)(wsb + WF_B);

    hipMemsetAsync(yb, 0, (size_t)NB * CCH * HO * HO * sizeof(float), stream);
    wprep_k<<<(64 * 9 * 128) / 256, 256, 0, stream>>>(fw, Wf);

    for (int n = 0; n < NB; n++) {
        hipMemsetAsync(T, 0, (size_t)LL * LL * sizeof(float), stream);
        build_P_k<<<(LL * KP) / 256, 256, 0, stream>>>(x2, Phi, Plo, n);
        norms_mm_k<<<LL / 4, 256, 0, stream>>>(x2, mask, rnorm, mmb, n);
        gemm1_k<<<dim3(18, 18, 2), 256, 0, stream>>>(Phi, Plo, T, n);
        softmax_k<<<LL, 256, 0, stream>>>(T, Tb, rnorm, mmb, mask_all, n);
        build_W_k<<<(KW * LL) / 256, 256, 0, stream>>>(x1, Wt, n);
        gemm2_k<<<dim3(18, 16, 4), 256, 0, stream>>>(Tb, Wt, yb, n);
    }
    y2bf_k<<<NB * PIX / 32, 256, 0, stream>>>(yb, yT);
    fuse_mfma_k<<<dim3(PIX / 64, 4, NB), 256, 0, stream>>>(yT, Wf, fb, out);
}

// Round 5
// 497.725 us; speedup vs baseline: 1.3746x; 1.3746x over previous
//
#include <hip/hip_runtime.h>
#include <math.h>

typedef unsigned short u16;
typedef unsigned int   u32;
typedef float f32x4 __attribute__((ext_vector_type(4)));
typedef short bfx8  __attribute__((ext_vector_type(8)));

#define NB   2
#define CCH  128
#define HS   48
#define LL   2304        // 48*48
#define KP   1152        // 128*3*3
#define KW   2048        // 128*4*4
#define HO   96
#define PIX  9216        // 96*96
#define TB_LD 4608       // Tb (bf16 attention) row stride in u16 elements

// Workspace byte offsets (total ~46.2 MB; 60.2 MB known-safe)
#define PHI_B 0                  // P hi bf16: 2304*1152*2 = 5,308,416 | V bf16 (2304*2048*2=9,437,184) aliases Phi+Plo during gemm2/gather
#define PLO_B 5308416            // P lo bf16
#define WT_B  10616832           // W^T bf16 [f'=tap*128+c][l]: 9,437,184
#define T_B   20054016           // T fp32 2304*2304*4 = 21,233,664 (bf16 Tb aliased, row stride 4608 u16)
#define YT_B  41287680           // yT bf16 [2][9216][128] = 4,718,592
#define WF_B  46006272           // fuse weights bf16 [64][9][128] = 147,456
#define NRM_B 46153728           // 1/norms: 2*2304*4
#define MM_B  46172160           // mm flags: 2*2304*4

__device__ __forceinline__ u16 f2bf(float f) {      // round-to-nearest-even
    u32 u = __float_as_uint(f);
    u32 r = (u + 0x7fffu + ((u >> 16) & 1u)) >> 16;
    return (u16)r;
}
__device__ __forceinline__ float bf2f(u16 h) {
    return __uint_as_float(((u32)h) << 16);
}
__device__ __forceinline__ void gll16(const void* g, void* l) {
    __builtin_amdgcn_global_load_lds((const __attribute__((address_space(1))) void*)g,
                                     (__attribute__((address_space(3))) void*)l, 16, 0, 0);
}

// ---------------------------------------------------------------------------
__global__ __launch_bounds__(256) void build_P_k(const float* __restrict__ x2,
                                                 u16* __restrict__ Ph, u16* __restrict__ Pl, int n) {
    int idx = blockIdx.x * 256 + threadIdx.x;
    int k = idx % KP, p = idx / KP;
    int c = k / 9, t = k - c * 9;
    int di = t / 3, dj = t - di * 3;
    int i = p / HS, j = p - (p / HS) * HS;
    int ii = i + di - 1, jj = j + dj - 1;
    float v = 0.0f;
    if (ii >= 0 && ii < HS && jj >= 0 && jj < HS)
        v = x2[((n * CCH + c) * HS + ii) * HS + jj];
    u16 h = f2bf(v);
    Ph[idx] = h;
    Pl[idx] = f2bf(v - bf2f(h));
}

// ---------------------------------------------------------------------------
__global__ __launch_bounds__(256) void norms_mm_k(const float* __restrict__ x2,
                                                  const float* __restrict__ mask,
                                                  float* __restrict__ rnorm,
                                                  float* __restrict__ mmb, int n) {
    int wid  = (blockIdx.x * 256 + threadIdx.x) >> 6;
    int lane = threadIdx.x & 63;
    if (wid >= LL) return;
    int i = wid / HS, j = wid - (wid / HS) * HS;
    float s = 0.0f;
    for (int k = lane; k < KP; k += 64) {
        int c = k / 9, t = k - (k / 9) * 9;
        int di = t / 3, dj = t - di * 3;
        int ii = i + di - 1, jj = j + dj - 1;
        if (ii >= 0 && ii < HS && jj >= 0 && jj < HS) {
            float x = x2[((n * CCH + c) * HS + ii) * HS + jj];
            s += x * x;
        }
    }
    #pragma unroll
    for (int o = 32; o; o >>= 1) s += __shfl_down(s, o);
    if (lane == 0) {
        rnorm[n * LL + wid] = 1.0f / fmaxf(sqrtf(s), 1e-4f);
        float msum = 0.0f;
        for (int di = -1; di <= 1; di++)
            for (int dj = -1; dj <= 1; dj++) {
                int ii = i + di, jj = j + dj;
                if (ii >= 0 && ii < HS && jj >= 0 && jj < HS)
                    msum += mask[(n * HS + ii) * HS + jj];
            }
        mmb[n * LL + wid] = (msum == 0.0f) ? 1.0f : 0.0f;
    }
}

// ---------------------------------------------------------------------------
// T[p][l] = P[p].P[l] (un-normalized), split-bf16 MFMA, full K per block.
// Tile 64(M)x128(N), 4 waves of 32x64. Conflict-free K-major LDS groups.
__global__ __launch_bounds__(256) void gemm1_k(const u16* __restrict__ Ph, const u16* __restrict__ Pl,
                                               float* __restrict__ T) {
    __shared__ __align__(16) u16 Ah[2048], Al[2048], Bh[4096], Bl[4096];
    int tid = threadIdx.x, w = tid >> 6, lane = tid & 63;
    int m0 = blockIdx.x * 64, n0 = blockIdx.y * 128;
    int srow = lane & 15, sk = (lane >> 4) * 8;
    size_t a1 = (size_t)(m0 + w * 16 + srow) * KP + sk;
    size_t b1 = (size_t)(n0 + w * 16 + srow) * KP + sk;
    size_t b2 = b1 + (size_t)64 * KP;
    int wm = (w >> 1) * 32, wn = (w & 1) * 64;
    int ga = (w >> 1) * 2, gb = (w & 1) * 4;
    f32x4 acc[2][4];
    #pragma unroll
    for (int i = 0; i < 2; i++)
        #pragma unroll
        for (int j = 0; j < 4; j++) acc[i][j] = (f32x4)0.0f;

    for (int k0 = 0; k0 < KP; k0 += 32) {
        if (k0) __syncthreads();
        gll16(Ph + a1 + k0, Ah + w * 512);
        gll16(Pl + a1 + k0, Al + w * 512);
        gll16(Ph + b1 + k0, Bh + w * 512);
        gll16(Ph + b2 + k0, Bh + (w + 4) * 512);
        gll16(Pl + b1 + k0, Bl + w * 512);
        gll16(Pl + b2 + k0, Bl + (w + 4) * 512);
        __syncthreads();
        bfx8 ah[2], al[2], bh[4], bl[4];
        #pragma unroll
        for (int i = 0; i < 2; i++) {
            ah[i] = *(const bfx8*)&Ah[(ga + i) * 512 + lane * 8];
            al[i] = *(const bfx8*)&Al[(ga + i) * 512 + lane * 8];
        }
        #pragma unroll
        for (int j = 0; j < 4; j++) {
            bh[j] = *(const bfx8*)&Bh[(gb + j) * 512 + lane * 8];
            bl[j] = *(const bfx8*)&Bl[(gb + j) * 512 + lane * 8];
        }
        #pragma unroll
        for (int i = 0; i < 2; i++)
            #pragma unroll
            for (int j = 0; j < 4; j++) {
                acc[i][j] = __builtin_amdgcn_mfma_f32_16x16x32_bf16(ah[i], bh[j], acc[i][j], 0, 0, 0);
                acc[i][j] = __builtin_amdgcn_mfma_f32_16x16x32_bf16(ah[i], bl[j], acc[i][j], 0, 0, 0);
                acc[i][j] = __builtin_amdgcn_mfma_f32_16x16x32_bf16(al[i], bh[j], acc[i][j], 0, 0, 0);
            }
    }
    #pragma unroll
    for (int j = 0; j < 4; j++) {
        int col = n0 + wn + j * 16 + (lane & 15);
        #pragma unroll
        for (int i = 0; i < 2; i++) {
            int rbase = m0 + wm + i * 16 + (lane >> 4) * 4;
            #pragma unroll
            for (int r = 0; r < 4; r++)
                T[(size_t)(rbase + r) * LL + col] = acc[i][j][r];
        }
    }
}

// ---------------------------------------------------------------------------
// Row softmax; applies 1/norm per column (gemm1 is un-normalized).
__global__ __launch_bounds__(256) void softmax_k(const float* __restrict__ T,
                                                 u16* __restrict__ Tb,
                                                 const float* __restrict__ rnorm,
                                                 const float* __restrict__ mmb,
                                                 const float* __restrict__ mask_all, int n) {
    int p = blockIdx.x, tid = threadIdx.x;
    __shared__ float red[8];
    const float* row = T + (size_t)p * LL;
    u16* orow = Tb + (size_t)p * TB_LD;
    float ma = mask_all[n * LL + p];
    float v[9], mmr[9];
    float mx = -3.0e38f;
    #pragma unroll
    for (int e = 0; e < 9; e++) {
        int l = tid + e * 256;
        float m_ = mmb[n * LL + l];
        mmr[e] = m_;
        float s = row[l] * rnorm[n * LL + l] * m_ * ma * 10.0f;
        v[e] = s;
        mx = fmaxf(mx, s);
    }
    #pragma unroll
    for (int o = 32; o; o >>= 1) mx = fmaxf(mx, __shfl_down(mx, o));
    int wid = tid >> 6, lane = tid & 63;
    if (lane == 0) red[wid] = mx;
    __syncthreads();
    mx = fmaxf(fmaxf(red[0], red[1]), fmaxf(red[2], red[3]));
    float sum = 0.0f;
    #pragma unroll
    for (int e = 0; e < 9; e++) { v[e] = __expf(v[e] - mx); sum += v[e]; }
    #pragma unroll
    for (int o = 32; o; o >>= 1) sum += __shfl_down(sum, o);
    if (lane == 0) red[4 + wid] = sum;
    __syncthreads();
    float inv = 1.0f / (red[4] + red[5] + red[6] + red[7]);
    int pi = p / HS, pj = p - (p / HS) * HS;
    #pragma unroll
    for (int e = 0; e < 9; e++) {
        int l = tid + e * 256;
        int li = l / HS, lj = l - (l / HS) * HS;
        bool nb = (li == pi && (lj == pj - 1 || lj == pj + 1)) ||
                  (lj == pj && (li == pi - 1 || li == pi + 1));
        float z = v[e] * inv * (nb ? 1.5f : 1.0f) * mmr[e] * ma;
        orow[l] = f2bf(fmaxf(z, 1e-8f));
    }
}

// ---------------------------------------------------------------------------
// W^T[f'][l], f' = tap*128 + c (tap-major so the gather over c is contiguous).
__global__ __launch_bounds__(256) void build_W_k(const float* __restrict__ x1,
                                                 u16* __restrict__ Wt, int n) {
    int idx = blockIdx.x * 256 + threadIdx.x;
    int l = idx % LL, f = idx / LL;
    int c = f & 127, tap = f >> 7;
    int ky = tap >> 2, kx = tap & 3;
    int li = l / HS, lj = l - (l / HS) * HS;
    int yy = 2 * li - 1 + ky, xx = 2 * lj - 1 + kx;
    float v = 0.0f;
    if (yy >= 0 && yy < HO && xx >= 0 && xx < HO)
        v = x1[((n * CCH + c) * HO + yy) * HO + xx];
    Wt[idx] = f2bf(v);
}

// ---------------------------------------------------------------------------
// V[p][f'] = 0.25 * sum_l Tb[p][l]*Wt[f'][l], plain bf16 store (no atomics).
// Tile 64(M)x128(N), full K. Grid 36x16 = 576 blocks.
__global__ __launch_bounds__(256) void gemm2_k(const u16* __restrict__ Tb, const u16* __restrict__ Wt,
                                               u16* __restrict__ V) {
    __shared__ __align__(16) u16 As[2048], Bs[4096];
    int tid = threadIdx.x, w = tid >> 6, lane = tid & 63;
    int m0 = blockIdx.x * 64, n0 = blockIdx.y * 128;
    int srow = lane & 15, sk = (lane >> 4) * 8;
    size_t a1 = (size_t)(m0 + w * 16 + srow) * TB_LD + sk;
    size_t b1 = (size_t)(n0 + w * 16 + srow) * LL + sk;
    size_t b2 = b1 + (size_t)64 * LL;
    int wm = (w >> 1) * 32, wn = (w & 1) * 64;
    int ga = (w >> 1) * 2, gb = (w & 1) * 4;
    f32x4 acc[2][4];
    #pragma unroll
    for (int i = 0; i < 2; i++)
        #pragma unroll
        for (int j = 0; j < 4; j++) acc[i][j] = (f32x4)0.0f;

    for (int k0 = 0; k0 < LL; k0 += 32) {
        if (k0) __syncthreads();
        gll16(Tb + a1 + k0, As + w * 512);
        gll16(Wt + b1 + k0, Bs + w * 512);
        gll16(Wt + b2 + k0, Bs + (w + 4) * 512);
        __syncthreads();
        bfx8 af[2], bf[4];
        #pragma unroll
        for (int i = 0; i < 2; i++) af[i] = *(const bfx8*)&As[(ga + i) * 512 + lane * 8];
        #pragma unroll
        for (int j = 0; j < 4; j++) bf[j] = *(const bfx8*)&Bs[(gb + j) * 512 + lane * 8];
        #pragma unroll
        for (int i = 0; i < 2; i++)
            #pragma unroll
            for (int j = 0; j < 4; j++)
                acc[i][j] = __builtin_amdgcn_mfma_f32_16x16x32_bf16(af[i], bf[j], acc[i][j], 0, 0, 0);
    }
    #pragma unroll
    for (int j = 0; j < 4; j++) {
        int f = n0 + wn + j * 16 + (lane & 15);
        #pragma unroll
        for (int i = 0; i < 2; i++) {
            int rbase = m0 + wm + i * 16 + (lane >> 4) * 4;
            #pragma unroll
            for (int r = 0; r < 4; r++)
                V[(size_t)(rbase + r) * KW + f] = f2bf(0.25f * acc[i][j][r]);
        }
    }
}

// ---------------------------------------------------------------------------
// Overlap-add gather: yT[n][pix][c] = sum of <=4 V contributions (0.25 folded).
// For output pixel yy: ky in {(yy+1)&1, +2}, pi=(yy+1-ky)/2; same for xx.
__global__ __launch_bounds__(256) void gather_k(const u16* __restrict__ V,
                                                u16* __restrict__ yT, int n) {
    int idx = blockIdx.x * 256 + threadIdx.x;      // PIX*128
    int c = idx & 127, pix = idx >> 7;
    int yy = pix / HO, xx = pix - yy * HO;
    int ky0 = (yy + 1) & 1, kx0 = (xx + 1) & 1;
    float s = 0.0f;
    #pragma unroll
    for (int a = 0; a < 2; a++) {
        int ky = ky0 + a * 2;
        int py = yy + 1 - ky;                      // = 2*pi, even by construction
        if (py < 0 || py >= HO) continue;
        int pi = py >> 1;
        #pragma unroll
        for (int b = 0; b < 2; b++) {
            int kx = kx0 + b * 2;
            int px = xx + 1 - kx;
            if (px < 0 || px >= HO) continue;
            int pj = px >> 1;
            s += bf2f(V[(size_t)(pi * HS + pj) * KW + (ky * 4 + kx) * 128 + c]);
        }
    }
    yT[(size_t)(n * PIX + pix) * CCH + c] = f2bf(s);
}

// ---------------------------------------------------------------------------
__global__ __launch_bounds__(256) void wprep_k(const float* __restrict__ fw,
                                               u16* __restrict__ Wf) {
    int idx = blockIdx.x * 256 + threadIdx.x;
    int c = idx & 127;
    int tap = (idx >> 7) % 9;
    int go = idx / (128 * 9);
    Wf[idx] = f2bf(fw[((size_t)go * 128 + c) * 9 + tap]);
}

// ---------------------------------------------------------------------------
__global__ __launch_bounds__(256) void fuse_mfma_k(const u16* __restrict__ yT,
                                                   const u16* __restrict__ Wf,
                                                   const float* __restrict__ fb,
                                                   float* __restrict__ out) {
    int n = blockIdx.z, g = blockIdx.y;
    const int d = 1 << g;
    int tid = threadIdx.x, wv = tid >> 6, lane = tid & 63;
    int pix0 = blockIdx.x * 64 + wv * 16;
    int h = pix0 / HO, w0 = pix0 - h * HO;
    int m = lane & 15, q = lane >> 4;
    int oc = m;
    const u16* brow = Wf + ((size_t)(g * 16 + oc) * 9) * CCH + q * 8;
    f32x4 acc = (f32x4)0.0f;

    #pragma unroll
    for (int tap = 0; tap < 9; tap++) {
        int dy = (tap / 3 - 1) * d, dx = (tap % 3 - 1) * d;
        int hh = h + dy;
        int ww = w0 + m + dx;
        bool v = (hh >= 0) & (hh < HO) & (ww >= 0) & (ww < HO);
        const u16* arow = yT + ((size_t)(n * PIX + hh * HO + ww)) * CCH + q * 8;
        const u16* bt = brow + tap * CCH;
        #pragma unroll
        for (int c0 = 0; c0 < CCH; c0 += 32) {
            bfx8 af = (bfx8)0;
            if (v) af = *(const bfx8*)(arow + c0);
            bfx8 bf = *(const bfx8*)(bt + c0);
            acc = __builtin_amdgcn_mfma_f32_16x16x32_bf16(af, bf, acc, 0, 0, 0);
        }
    }
    float bias = fb[g * 16 + oc];
    f32x4 o;
    #pragma unroll
    for (int r = 0; r < 4; r++) o[r] = fmaxf(acc[r] + bias, 0.0f);
    size_t oi = ((size_t)(n * 64 + g * 16 + oc)) * PIX + pix0 + q * 4;
    *(f32x4*)&out[oi] = o;
}

// ---------------------------------------------------------------------------
extern "C" void kernel_launch(void* const* d_in, const int* in_sizes, int n_in,
                              void* d_out, int out_size, void* d_ws, size_t ws_size,
                              hipStream_t stream) {
    const float* x1       = (const float*)d_in[0];
    const float* x2       = (const float*)d_in[1];
    const float* mask     = (const float*)d_in[2];
    const float* mask_all = (const float*)d_in[3];
    const float* fw       = (const float*)d_in[4];
    const float* fb       = (const float*)d_in[5];
    float* out = (float*)d_out;
    char* wsb  = (char*)d_ws;

    u16*   Phi   = (u16*)(wsb + PHI_B);
    u16*   Plo   = (u16*)(wsb + PLO_B);
    u16*   V     = (u16*)(wsb + PHI_B);    // aliases Phi+Plo (dead during gemm2/gather)
    u16*   Wt    = (u16*)(wsb + WT_B);
    float* T     = (float*)(wsb + T_B);
    u16*   Tb    = (u16*)(wsb + T_B);
    u16*   yT    = (u16*)(wsb + YT_B);
    u16*   Wf    = (u16*)(wsb + WF_B);
    float* rnorm = (float*)(wsb + NRM_B);
    float* mmb   = (float*)(wsb + MM_B);

    wprep_k<<<(64 * 9 * 128) / 256, 256, 0, stream>>>(fw, Wf);

    for (int n = 0; n < NB; n++) {
        build_P_k<<<(LL * KP) / 256, 256, 0, stream>>>(x2, Phi, Plo, n);
        norms_mm_k<<<LL / 4, 256, 0, stream>>>(x2, mask, rnorm, mmb, n);
        gemm1_k<<<dim3(36, 18), 256, 0, stream>>>(Phi, Plo, T);
        softmax_k<<<LL, 256, 0, stream>>>(T, Tb, rnorm, mmb, mask_all, n);
        build_W_k<<<(KW * LL) / 256, 256, 0, stream>>>(x1, Wt, n);
        gemm2_k<<<dim3(36, 16), 256, 0, stream>>>(Tb, Wt, V);
        gather_k<<<(PIX * 128) / 256, 256, 0, stream>>>(V, yT, n);
    }
    fuse_mfma_k<<<dim3(PIX / 64, 4, NB), 256, 0, stream>>>(yT, Wf, fb, out);
}

// Round 6
// 412.651 us; speedup vs baseline: 1.6579x; 1.2062x over previous
//
#include <hip/hip_runtime.h>
#include <math.h>

typedef unsigned short u16;
typedef unsigned int   u32;
typedef float f32x4 __attribute__((ext_vector_type(4)));
typedef short bfx8  __attribute__((ext_vector_type(8)));

#define NB   2
#define CCH  128
#define HS   48
#define LL   2304        // 48*48
#define KW   2048        // 128*4*4
#define HO   96
#define PIX  9216        // 96*96
#define VHALF ((size_t)LL * KW)   // elements per split-K V buffer

// Workspace byte offsets (total ~45.2 MB; 60.2 MB known-safe)
#define XTH_B 0                  // x2^T hi bf16 [2304][128] = 589,824
#define XTL_B 589824             // x2^T lo bf16
#define PXN_B 1179648            // per-pixel sqnorm fp32 [2304]
#define NRM_B 1188864            // 1/norms fp32 [2][2304]
#define MM_B  1207296            // mm flags fp32 [2][2304]
#define WF_B  1225728            // fuse weights bf16 [64][9][128] = 147,456
#define WT_B  1373184            // W^T bf16 [f'=tap*128+c][2304] = 9,437,184
#define S_B   10810368           // S fp32 [2304][2304] = 21,233,664 ; V0/V1 bf16 (2x9,437,184) alias this region after softmax
#define TB_B  32044032           // Tb bf16 [2304][2304] = 10,616,832
#define YT_B  42660864           // yT bf16 [2][9216][128] = 4,718,592

__device__ __forceinline__ u16 f2bf(float f) {      // round-to-nearest-even
    u32 u = __float_as_uint(f);
    u32 r = (u + 0x7fffu + ((u >> 16) & 1u)) >> 16;
    return (u16)r;
}
__device__ __forceinline__ float bf2f(u16 h) {
    return __uint_as_float(((u32)h) << 16);
}
__device__ __forceinline__ void gll16(const void* g, void* l) {
    __builtin_amdgcn_global_load_lds((const __attribute__((address_space(1))) void*)g,
                                     (__attribute__((address_space(3))) void*)l, 16, 0, 0);
}

// ---------------------------------------------------------------------------
// x2 [c][pix] fp32 -> Xt hi/lo bf16 [pix][c] (LDS transpose), one batch.
__global__ __launch_bounds__(256) void xprep_k(const float* __restrict__ x2,
                                               u16* __restrict__ Xh, u16* __restrict__ Xl, int n) {
    __shared__ float lt[32][130];
    int pix0 = blockIdx.x * 32;
    int tid = threadIdx.x;
    #pragma unroll
    for (int i = tid; i < 32 * 128; i += 256) {
        int c = i >> 5, p = i & 31;
        lt[p][c] = x2[((size_t)(n * CCH + c)) * LL + pix0 + p];
    }
    __syncthreads();
    #pragma unroll
    for (int i = tid; i < 32 * 128; i += 256) {
        int p = i >> 7, c = i & 127;
        float v = lt[p][c];
        u16 h = f2bf(v);
        Xh[(size_t)(pix0 + p) * CCH + c] = h;
        Xl[(size_t)(pix0 + p) * CCH + c] = f2bf(v - bf2f(h));
    }
}

// Per-pixel channel sq-norm (fp32, from x2 directly).
__global__ __launch_bounds__(256) void pixnorm_k(const float* __restrict__ x2,
                                                 float* __restrict__ pxn, int n) {
    int pix = blockIdx.x * 256 + threadIdx.x;       // 9 blocks, exactly LL
    float s = 0.0f;
    for (int c = 0; c < CCH; c++) {
        float v = x2[((size_t)(n * CCH + c)) * LL + pix];
        s += v * v;
    }
    pxn[pix] = s;
}

// rnorm[p] = 1/max(sqrt(3x3 boxsum of pxn), 1e-4); mm flag from mask boxsum.
__global__ __launch_bounds__(256) void boxnorm_k(const float* __restrict__ pxn,
                                                 const float* __restrict__ mask,
                                                 float* __restrict__ rnorm,
                                                 float* __restrict__ mmb, int n) {
    int p = blockIdx.x * 256 + threadIdx.x;         // 9 blocks, exactly LL
    int i = p / HS, j = p - (p / HS) * HS;
    float s = 0.0f, msum = 0.0f;
    for (int di = -1; di <= 1; di++)
        for (int dj = -1; dj <= 1; dj++) {
            int ii = i + di, jj = j + dj;
            if (ii >= 0 && ii < HS && jj >= 0 && jj < HS) {
                s += pxn[ii * HS + jj];
                msum += mask[(n * HS + ii) * HS + jj];
            }
        }
    rnorm[n * LL + p] = 1.0f / fmaxf(sqrtf(s), 1e-4f);
    mmb[n * LL + p] = (msum == 0.0f) ? 1.0f : 0.0f;
}

// ---------------------------------------------------------------------------
// S[u][v] = Xt[u].Xt[v], M=N=2304, K=128, split-bf16 (3 MFMA). 128x128 tile,
// 4 waves of 64x64. Conflict-free K-major LDS groups (verified r4/r5).
__global__ __launch_bounds__(256) void sgemm_k(const u16* __restrict__ Xh, const u16* __restrict__ Xl,
                                               float* __restrict__ S) {
    __shared__ __align__(16) u16 Ah[4096], Al[4096], Bh[4096], Bl[4096];
    int tid = threadIdx.x, w = tid >> 6, lane = tid & 63;
    int m0 = blockIdx.x * 128, n0 = blockIdx.y * 128;
    int srow = lane & 15, sk = (lane >> 4) * 8;
    size_t a1 = (size_t)(m0 + w * 16 + srow) * CCH + sk;
    size_t a2 = a1 + (size_t)64 * CCH;
    size_t b1 = (size_t)(n0 + w * 16 + srow) * CCH + sk;
    size_t b2 = b1 + (size_t)64 * CCH;
    int wm = (w >> 1) * 64, wn = (w & 1) * 64;
    int ga = (w >> 1) * 4, gb = (w & 1) * 4;
    f32x4 acc[4][4];
    #pragma unroll
    for (int i = 0; i < 4; i++)
        #pragma unroll
        for (int j = 0; j < 4; j++) acc[i][j] = (f32x4)0.0f;

    for (int k0 = 0; k0 < CCH; k0 += 32) {
        if (k0) __syncthreads();
        gll16(Xh + a1 + k0, Ah + w * 512);
        gll16(Xh + a2 + k0, Ah + (w + 4) * 512);
        gll16(Xl + a1 + k0, Al + w * 512);
        gll16(Xl + a2 + k0, Al + (w + 4) * 512);
        gll16(Xh + b1 + k0, Bh + w * 512);
        gll16(Xh + b2 + k0, Bh + (w + 4) * 512);
        gll16(Xl + b1 + k0, Bl + w * 512);
        gll16(Xl + b2 + k0, Bl + (w + 4) * 512);
        __syncthreads();
        bfx8 ah[4], al[4], bh[4], bl[4];
        #pragma unroll
        for (int i = 0; i < 4; i++) {
            ah[i] = *(const bfx8*)&Ah[(ga + i) * 512 + lane * 8];
            al[i] = *(const bfx8*)&Al[(ga + i) * 512 + lane * 8];
        }
        #pragma unroll
        for (int j = 0; j < 4; j++) {
            bh[j] = *(const bfx8*)&Bh[(gb + j) * 512 + lane * 8];
            bl[j] = *(const bfx8*)&Bl[(gb + j) * 512 + lane * 8];
        }
        #pragma unroll
        for (int i = 0; i < 4; i++)
            #pragma unroll
            for (int j = 0; j < 4; j++) {
                acc[i][j] = __builtin_amdgcn_mfma_f32_16x16x32_bf16(ah[i], bh[j], acc[i][j], 0, 0, 0);
                acc[i][j] = __builtin_amdgcn_mfma_f32_16x16x32_bf16(ah[i], bl[j], acc[i][j], 0, 0, 0);
                acc[i][j] = __builtin_amdgcn_mfma_f32_16x16x32_bf16(al[i], bh[j], acc[i][j], 0, 0, 0);
            }
    }
    #pragma unroll
    for (int j = 0; j < 4; j++) {
        int col = n0 + wn + j * 16 + (lane & 15);
        #pragma unroll
        for (int i = 0; i < 4; i++) {
            int rbase = m0 + wm + i * 16 + (lane >> 4) * 4;
            #pragma unroll
            for (int r = 0; r < 4; r++)
                S[(size_t)(rbase + r) * LL + col] = acc[i][j][r];
        }
    }
}

// ---------------------------------------------------------------------------
// Fused diagonal shift-sum (T[p][l] = sum_{3x3 delta} S[p+d, l+d]) + masked
// softmax + neighbor boost -> Tb bf16 row (stride 2304). One block per p.
__global__ __launch_bounds__(256) void softmax_k(const float* __restrict__ S,
                                                 u16* __restrict__ Tb,
                                                 const float* __restrict__ rnorm,
                                                 const float* __restrict__ mmb,
                                                 const float* __restrict__ mask_all, int n) {
    int p = blockIdx.x, tid = threadIdx.x;
    __shared__ float red[8];
    int pi = p / HS, pj = p - (p / HS) * HS;
    float ma = mask_all[n * LL + p];
    int li[9], lj[9];
    float v[9], mmr[9];
    #pragma unroll
    for (int e = 0; e < 9; e++) {
        int l = tid + e * 256;
        li[e] = l / HS; lj[e] = l - (l / HS) * HS;
        v[e] = 0.0f;
    }
    #pragma unroll
    for (int di = -1; di <= 1; di++)
        #pragma unroll
        for (int dj = -1; dj <= 1; dj++) {
            if ((u32)(pi + di) >= HS || (u32)(pj + dj) >= HS) continue;  // block-uniform
            int o = di * HS + dj;
            const float* Srow = S + (size_t)(p + o) * LL + o;
            #pragma unroll
            for (int e = 0; e < 9; e++) {
                int l = tid + e * 256;
                if ((u32)(li[e] + di) < HS && (u32)(lj[e] + dj) < HS)
                    v[e] += Srow[l];
            }
        }
    float mx = -3.0e38f;
    #pragma unroll
    for (int e = 0; e < 9; e++) {
        int l = tid + e * 256;
        float m_ = mmb[n * LL + l];
        mmr[e] = m_;
        float s = v[e] * rnorm[n * LL + l] * m_ * ma * 10.0f;
        v[e] = s;
        mx = fmaxf(mx, s);
    }
    #pragma unroll
    for (int o = 32; o; o >>= 1) mx = fmaxf(mx, __shfl_down(mx, o));
    int wid = tid >> 6, lane = tid & 63;
    if (lane == 0) red[wid] = mx;
    __syncthreads();
    mx = fmaxf(fmaxf(red[0], red[1]), fmaxf(red[2], red[3]));
    float sum = 0.0f;
    #pragma unroll
    for (int e = 0; e < 9; e++) { v[e] = __expf(v[e] - mx); sum += v[e]; }
    #pragma unroll
    for (int o = 32; o; o >>= 1) sum += __shfl_down(sum, o);
    if (lane == 0) red[4 + wid] = sum;
    __syncthreads();
    float inv = 1.0f / (red[4] + red[5] + red[6] + red[7]);
    u16* orow = Tb + (size_t)p * LL;
    #pragma unroll
    for (int e = 0; e < 9; e++) {
        int l = tid + e * 256;
        bool nb = (li[e] == pi && (lj[e] == pj - 1 || lj[e] == pj + 1)) ||
                  (lj[e] == pj && (li[e] == pi - 1 || li[e] == pi + 1));
        float z = v[e] * inv * (nb ? 1.5f : 1.0f) * mmr[e] * ma;
        orow[l] = f2bf(fmaxf(z, 1e-8f));
    }
}

// ---------------------------------------------------------------------------
// W^T[f'][l], f' = tap*128 + c (tap-major so the gather over c is contiguous).
__global__ __launch_bounds__(256) void build_W_k(const float* __restrict__ x1,
                                                 u16* __restrict__ Wt, int n) {
    int idx = blockIdx.x * 256 + threadIdx.x;
    int l = idx % LL, f = idx / LL;
    int c = f & 127, tap = f >> 7;
    int ky = tap >> 2, kx = tap & 3;
    int li = l / HS, lj = l - (l / HS) * HS;
    int yy = 2 * li - 1 + ky, xx = 2 * lj - 1 + kx;
    float v = 0.0f;
    if (yy >= 0 && yy < HO && xx >= 0 && xx < HO)
        v = x1[((n * CCH + c) * HO + yy) * HO + xx];
    Wt[idx] = f2bf(v);
}

// ---------------------------------------------------------------------------
// V[kb][p][f'] = 0.25 * sum_{l in K-half kb} Tb[p][l]*Wt[f'][l]. Split-K x2,
// separate output halves (no atomics). 128x128 tile, 4 waves of 64x64.
__global__ __launch_bounds__(256) void gemm2_k(const u16* __restrict__ Tb, const u16* __restrict__ Wt,
                                               u16* __restrict__ V) {
    __shared__ __align__(16) u16 As[4096], Bs[4096];
    int tid = threadIdx.x, w = tid >> 6, lane = tid & 63;
    int m0 = blockIdx.x * 128, n0 = blockIdx.y * 128;
    int koff = blockIdx.z * 1152;
    int srow = lane & 15, sk = (lane >> 4) * 8;
    size_t a1 = (size_t)(m0 + w * 16 + srow) * LL + koff + sk;
    size_t a2 = a1 + (size_t)64 * LL;
    size_t b1 = (size_t)(n0 + w * 16 + srow) * LL + koff + sk;
    size_t b2 = b1 + (size_t)64 * LL;
    int wm = (w >> 1) * 64, wn = (w & 1) * 64;
    int ga = (w >> 1) * 4, gb = (w & 1) * 4;
    f32x4 acc[4][4];
    #pragma unroll
    for (int i = 0; i < 4; i++)
        #pragma unroll
        for (int j = 0; j < 4; j++) acc[i][j] = (f32x4)0.0f;

    for (int k0 = 0; k0 < 1152; k0 += 32) {
        if (k0) __syncthreads();
        gll16(Tb + a1 + k0, As + w * 512);
        gll16(Tb + a2 + k0, As + (w + 4) * 512);
        gll16(Wt + b1 + k0, Bs + w * 512);
        gll16(Wt + b2 + k0, Bs + (w + 4) * 512);
        __syncthreads();
        bfx8 af[4], bf[4];
        #pragma unroll
        for (int i = 0; i < 4; i++) af[i] = *(const bfx8*)&As[(ga + i) * 512 + lane * 8];
        #pragma unroll
        for (int j = 0; j < 4; j++) bf[j] = *(const bfx8*)&Bs[(gb + j) * 512 + lane * 8];
        #pragma unroll
        for (int i = 0; i < 4; i++)
            #pragma unroll
            for (int j = 0; j < 4; j++)
                acc[i][j] = __builtin_amdgcn_mfma_f32_16x16x32_bf16(af[i], bf[j], acc[i][j], 0, 0, 0);
    }
    u16* Vb = V + (size_t)blockIdx.z * VHALF;
    #pragma unroll
    for (int j = 0; j < 4; j++) {
        int f = n0 + wn + j * 16 + (lane & 15);
        #pragma unroll
        for (int i = 0; i < 4; i++) {
            int rbase = m0 + wm + i * 16 + (lane >> 4) * 4;
            #pragma unroll
            for (int r = 0; r < 4; r++)
                Vb[(size_t)(rbase + r) * KW + f] = f2bf(0.25f * acc[i][j][r]);
        }
    }
}

// ---------------------------------------------------------------------------
// Overlap-add gather: yT[n][pix][c] = sum of <=4 contributions from each of
// the two split-K V halves (0.25 already folded).
__global__ __launch_bounds__(256) void gather_k(const u16* __restrict__ V,
                                                u16* __restrict__ yT, int n) {
    int idx = blockIdx.x * 256 + threadIdx.x;      // PIX*128
    int c = idx & 127, pix = idx >> 7;
    int yy = pix / HO, xx = pix - yy * HO;
    int ky0 = (yy + 1) & 1, kx0 = (xx + 1) & 1;
    float s = 0.0f;
    #pragma unroll
    for (int a = 0; a < 2; a++) {
        int ky = ky0 + a * 2;
        int py = yy + 1 - ky;
        if (py < 0 || py >= HO) continue;
        int pi = py >> 1;
        #pragma unroll
        for (int b = 0; b < 2; b++) {
            int kx = kx0 + b * 2;
            int px = xx + 1 - kx;
            if (px < 0 || px >= HO) continue;
            int pj = px >> 1;
            size_t off = (size_t)(pi * HS + pj) * KW + (ky * 4 + kx) * 128 + c;
            s += bf2f(V[off]) + bf2f(V[VHALF + off]);
        }
    }
    yT[(size_t)(n * PIX + pix) * CCH + c] = f2bf(s);
}

// ---------------------------------------------------------------------------
__global__ __launch_bounds__(256) void wprep_k(const float* __restrict__ fw,
                                               u16* __restrict__ Wf) {
    int idx = blockIdx.x * 256 + threadIdx.x;
    int c = idx & 127;
    int tap = (idx >> 7) % 9;
    int go = idx / (128 * 9);
    Wf[idx] = f2bf(fw[((size_t)go * 128 + c) * 9 + tap]);
}

// ---------------------------------------------------------------------------
__global__ __launch_bounds__(256) void fuse_mfma_k(const u16* __restrict__ yT,
                                                   const u16* __restrict__ Wf,
                                                   const float* __restrict__ fb,
                                                   float* __restrict__ out) {
    int n = blockIdx.z, g = blockIdx.y;
    const int d = 1 << g;
    int tid = threadIdx.x, wv = tid >> 6, lane = tid & 63;
    int pix0 = blockIdx.x * 64 + wv * 16;
    int h = pix0 / HO, w0 = pix0 - h * HO;
    int m = lane & 15, q = lane >> 4;
    int oc = m;
    const u16* brow = Wf + ((size_t)(g * 16 + oc) * 9) * CCH + q * 8;
    f32x4 acc = (f32x4)0.0f;

    #pragma unroll
    for (int tap = 0; tap < 9; tap++) {
        int dy = (tap / 3 - 1) * d, dx = (tap % 3 - 1) * d;
        int hh = h + dy;
        int ww = w0 + m + dx;
        bool v = (hh >= 0) & (hh < HO) & (ww >= 0) & (ww < HO);
        const u16* arow = yT + ((size_t)(n * PIX + hh * HO + ww)) * CCH + q * 8;
        const u16* bt = brow + tap * CCH;
        #pragma unroll
        for (int c0 = 0; c0 < CCH; c0 += 32) {
            bfx8 af = (bfx8)0;
            if (v) af = *(const bfx8*)(arow + c0);
            bfx8 bf = *(const bfx8*)(bt + c0);
            acc = __builtin_amdgcn_mfma_f32_16x16x32_bf16(af, bf, acc, 0, 0, 0);
        }
    }
    float bias = fb[g * 16 + oc];
    f32x4 o;
    #pragma unroll
    for (int r = 0; r < 4; r++) o[r] = fmaxf(acc[r] + bias, 0.0f);
    size_t oi = ((size_t)(n * 64 + g * 16 + oc)) * PIX + pix0 + q * 4;
    *(f32x4*)&out[oi] = o;
}

// ---------------------------------------------------------------------------
extern "C" void kernel_launch(void* const* d_in, const int* in_sizes, int n_in,
                              void* d_out, int out_size, void* d_ws, size_t ws_size,
                              hipStream_t stream) {
    const float* x1       = (const float*)d_in[0];
    const float* x2       = (const float*)d_in[1];
    const float* mask     = (const float*)d_in[2];
    const float* mask_all = (const float*)d_in[3];
    const float* fw       = (const float*)d_in[4];
    const float* fb       = (const float*)d_in[5];
    float* out = (float*)d_out;
    char* wsb  = (char*)d_ws;

    u16*   Xh    = (u16*)(wsb + XTH_B);
    u16*   Xl    = (u16*)(wsb + XTL_B);
    float* pxn   = (float*)(wsb + PXN_B);
    float* rnorm = (float*)(wsb + NRM_B);
    float* mmb   = (float*)(wsb + MM_B);
    u16*   Wf    = (u16*)(wsb + WF_B);
    u16*   Wt    = (u16*)(wsb + WT_B);
    float* S     = (float*)(wsb + S_B);
    u16*   V     = (u16*)(wsb + S_B);      // V0/V1 alias S (dead after softmax)
    u16*   Tb    = (u16*)(wsb + TB_B);
    u16*   yT    = (u16*)(wsb + YT_B);

    wprep_k<<<(64 * 9 * 128) / 256, 256, 0, stream>>>(fw, Wf);

    for (int n = 0; n < NB; n++) {
        xprep_k<<<LL / 32, 256, 0, stream>>>(x2, Xh, Xl, n);
        pixnorm_k<<<LL / 256, 256, 0, stream>>>(x2, pxn, n);
        boxnorm_k<<<LL / 256, 256, 0, stream>>>(pxn, mask, rnorm, mmb, n);
        sgemm_k<<<dim3(18, 18), 256, 0, stream>>>(Xh, Xl, S);
        softmax_k<<<LL, 256, 0, stream>>>(S, Tb, rnorm, mmb, mask_all, n);
        build_W_k<<<(KW * LL) / 256, 256, 0, stream>>>(x1, Wt, n);
        gemm2_k<<<dim3(18, 16, 2), 256, 0, stream>>>(Tb, Wt, V);
        gather_k<<<(PIX * 128) / 256, 256, 0, stream>>>(V, yT, n);
    }
    fuse_mfma_k<<<dim3(PIX / 64, 4, NB), 256, 0, stream>>>(yT, Wf, fb, out);
}